// Round 4
// baseline (218.594 us; speedup 1.0000x reference)
//
#include <hip/hip_runtime.h>
#include <math.h>

// Output = segment_softmax over logits that depend ONLY on the inputs part of
// combined @ W_k: the agg(segment-mean MLP) contribution is constant within a
// segment and cancels exactly in the segment softmax (shift invariance).
// wx[h][d] = sum_j Wk[d, h*64+j]*Wq[h,j] / 8;  logit[n,h] = x[n,:].wx[h,:];
// per-segment softmax; out[h*N + n].
//
// Round 7: wave-per-segment (1-wave blocks, no barriers) + LDS caches.
//  R3 post-mortem: block-per-segment was latency-bound (VALUBusy 10%, occ 9%)
//  on 160 ds_read_b32 wx broadcasts per row + 3 block barriers, 56us vs
//  round-0 wave-per-segment's ~30us. This version:
//   - 1 wave per segment, grid 2048x64: no barriers, no convoying.
//   - wx stored [NH][DIM] -> ds_read_b128 (4 vals/read), and 4 rows/lane
//     per pass share each read: 40 b128 per 64 rows vs 640 b32 (13x fewer
//     LDS cycles).
//   - logit/e cache in LDS cache[NH][512] (8KB): cross-pass, spill-proof
//     (R1/R2 showed register caches spill; R3 showed LDS cache works).

#define NROWS 500000
#define DIM 40
#define NQ (DIM / 4)     // 10 float4 per row
#define NSEG 2048
#define DOTD 64
#define NH 4
#define PBLOCK 256
#define CACHE_ROWS 512   // stat max segment len ~300 (binomial mean 244, sd 16)
#define RPL 4            // rows per lane per super-iteration (covers 256 rows)

// ---- prep: segment bounds (with gap fill for empty segments) + wx fold ----
__global__ __launch_bounds__(PBLOCK) void prep_kernel(
    const int* __restrict__ seg,    // [N], sorted
    const float* __restrict__ Wk,   // [168, 256]
    const float* __restrict__ Wq,   // [4, 64]
    int* __restrict__ seg_start,    // [NSEG]
    int* __restrict__ seg_end,      // [NSEG]
    float* __restrict__ wxg)        // [NH*DIM], layout h*DIM+d
{
    const int tid = (int)threadIdx.x;
    const int n = (int)(blockIdx.x * PBLOCK + tid);

    if (blockIdx.x == 0 && tid < DIM * NH) {
        const int h = tid / DIM;
        const int d = tid - h * DIM;
        const float* wkp = Wk + d * (NH * DOTD) + h * DOTD;
        const float* wqp = Wq + h * DOTD;
        float acc = 0.f;
        #pragma unroll
        for (int j = 0; j < DOTD; ++j) acc += wkp[j] * wqp[j];
        wxg[h * DIM + d] = acc * 0.125f;  // fold 1/sqrt(64)
    }

    if (n < NROWS) {
        const int s = seg[n];
        if (n == 0) {
            seg_start[s] = 0;
            for (int t = 0; t < s; ++t) { seg_start[t] = 0; seg_end[t] = 0; }
        } else {
            const int sp = seg[n - 1];
            if (sp != s) {
                seg_start[s] = n;
                seg_end[sp] = n;
                for (int t = sp + 1; t < s; ++t) { seg_start[t] = n; seg_end[t] = n; }
            }
        }
        if (n == NROWS - 1) {
            seg_end[s] = NROWS;
            for (int t = s + 1; t < NSEG; ++t) { seg_start[t] = NROWS; seg_end[t] = NROWS; }
        }
    }
}

// recompute logits for one row (fallback for rows beyond the LDS cache;
// statistically never taken: cache covers 512 rows, max segment ~300)
__device__ __forceinline__ void recompute_logits(
    const float4* __restrict__ x4, const float (*wxl)[DIM], int n, float* a)
{
    #pragma unroll
    for (int h = 0; h < NH; ++h) a[h] = 0.f;
    #pragma unroll
    for (int q = 0; q < NQ; ++q) {
        const float4 v = x4[(size_t)n * NQ + q];
        #pragma unroll
        for (int h = 0; h < NH; ++h) {
            const float4 w = ((const float4*)wxl[h])[q];
            a[h] += v.x * w.x + v.y * w.y + v.z * w.z + v.w * w.w;
        }
    }
}

// ---- main: one wave (=one 64-thread block) per segment ----
__global__ __launch_bounds__(64) void seg_attn_kernel(
    const float* __restrict__ x,          // [N, 40]
    const int* __restrict__ seg_start,
    const int* __restrict__ seg_end,
    const float* __restrict__ wxg,        // [NH*DIM]
    float* __restrict__ out)              // [4, N]
{
    __shared__ __align__(16) float wxl[NH][DIM];   // 640 B
    __shared__ float cache[NH][CACHE_ROWS];        // 8 KB logit->e cache

    const int lane = (int)threadIdx.x;
    const int s = (int)blockIdx.x;
    const int start = seg_start[s];
    const int rows = seg_end[s] - start;
    if (rows <= 0) return;   // uniform for the whole (1-wave) block

    {   // stage wx (flat copy; wxg already [NH][DIM])
        float* wf = &wxl[0][0];
        for (int t = lane; t < NH * DIM; t += 64) wf[t] = wxg[t];
    }
    __syncthreads();   // 1-wave block: cheap; orders cross-lane LDS wx reads

    const float4* x4 = (const float4*)x;
    const int sup = (rows + 255) >> 8;   // super-iterations of 256 rows

    // ---- pass 1: logits (4 rows/lane share each wx b128 read) ----
    float lmax[NH];
    #pragma unroll
    for (int h = 0; h < NH; ++h) lmax[h] = -3.0e38f;

    for (int si = 0; si < sup; ++si) {
        const int base = (si << 8) + lane;
        float acc[RPL][NH];
        #pragma unroll
        for (int k = 0; k < RPL; ++k)
            #pragma unroll
            for (int h = 0; h < NH; ++h) acc[k][h] = 0.f;

        #pragma unroll
        for (int q = 0; q < NQ; ++q) {
            float4 w[NH];
            #pragma unroll
            for (int h = 0; h < NH; ++h) w[h] = ((const float4*)wxl[h])[q];
            #pragma unroll
            for (int k = 0; k < RPL; ++k) {
                const int i = base + (k << 6);
                if (i < rows) {
                    const float4 v = x4[(size_t)(start + i) * NQ + q];
                    #pragma unroll
                    for (int h = 0; h < NH; ++h)
                        acc[k][h] += v.x * w[h].x + v.y * w[h].y
                                   + v.z * w[h].z + v.w * w[h].w;
                }
            }
        }
        #pragma unroll
        for (int k = 0; k < RPL; ++k) {
            const int i = base + (k << 6);
            if (i < rows) {
                #pragma unroll
                for (int h = 0; h < NH; ++h) {
                    if (i < CACHE_ROWS) cache[h][i] = acc[k][h];
                    lmax[h] = fmaxf(lmax[h], acc[k][h]);
                }
            }
        }
    }

    // ---- wave max reduce ----
    float m[NH];
    #pragma unroll
    for (int h = 0; h < NH; ++h) {
        float v = lmax[h];
        #pragma unroll
        for (int off = 32; off > 0; off >>= 1) v = fmaxf(v, __shfl_xor(v, off, 64));
        m[h] = v;
    }

    // ---- pass 2: e = exp(l-m) (store back to cache) + wave sum ----
    float lsum[NH] = {0.f, 0.f, 0.f, 0.f};
    for (int si = 0; si < sup; ++si) {
        const int base = (si << 8) + lane;
        #pragma unroll
        for (int k = 0; k < RPL; ++k) {
            const int i = base + (k << 6);
            if (i < rows) {
                if (i < CACHE_ROWS) {
                    #pragma unroll
                    for (int h = 0; h < NH; ++h) {
                        const float e = __expf(cache[h][i] - m[h]);
                        cache[h][i] = e;
                        lsum[h] += e;
                    }
                } else {  // stat-never fallback
                    float a[NH];
                    recompute_logits(x4, wxl, start + i, a);
                    #pragma unroll
                    for (int h = 0; h < NH; ++h) lsum[h] += __expf(a[h] - m[h]);
                }
            }
        }
    }
    float rden[NH];
    #pragma unroll
    for (int h = 0; h < NH; ++h) {
        float v = lsum[h];
        #pragma unroll
        for (int off = 32; off > 0; off >>= 1) v += __shfl_xor(v, off, 64);
        rden[h] = 1.0f / v;
    }

    // ---- pass 3: write normalized outputs (coalesced per h) ----
    for (int si = 0; si < sup; ++si) {
        const int base = (si << 8) + lane;
        #pragma unroll
        for (int k = 0; k < RPL; ++k) {
            const int i = base + (k << 6);
            if (i < rows) {
                const int n = start + i;
                if (i < CACHE_ROWS) {
                    #pragma unroll
                    for (int h = 0; h < NH; ++h)
                        out[(size_t)h * NROWS + n] = cache[h][i] * rden[h];
                } else {  // stat-never fallback
                    float a[NH];
                    recompute_logits(x4, wxl, n, a);
                    #pragma unroll
                    for (int h = 0; h < NH; ++h)
                        out[(size_t)h * NROWS + n] = __expf(a[h] - m[h]) * rden[h];
                }
            }
        }
    }
}

extern "C" void kernel_launch(void* const* d_in, const int* in_sizes, int n_in,
                              void* d_out, int out_size, void* d_ws, size_t ws_size,
                              hipStream_t stream) {
    const float* x  = (const float*)d_in[0];
    const int* seg  = (const int*)d_in[1];
    const float* Wk = (const float*)d_in[11];
    const float* Wq = (const float*)d_in[12];
    float* out = (float*)d_out;

    int* seg_start = (int*)d_ws;                  // [NSEG]
    int* seg_end   = seg_start + NSEG;            // [NSEG]
    float* wxg     = (float*)(seg_end + NSEG);    // [NH*DIM]

    hipLaunchKernelGGL(prep_kernel, dim3((NROWS + PBLOCK - 1) / PBLOCK), dim3(PBLOCK),
                       0, stream, seg, Wk, Wq, seg_start, seg_end, wxg);
    hipLaunchKernelGGL(seg_attn_kernel, dim3(NSEG), dim3(64),
                       0, stream, x, seg_start, seg_end, wxg, out);
}

// Round 5
// 172.105 us; speedup vs baseline: 1.2701x; 1.2701x over previous
//
#include <hip/hip_runtime.h>
#include <math.h>

// Output = segment_softmax over logits that depend ONLY on the inputs part of
// combined @ W_k: the agg(segment-mean MLP) contribution is constant within a
// segment and cancels exactly in the segment softmax (shift invariance).
// wx[h][d] = sum_j Wk[d, h*64+j]*Wq[h,j] / 8;  logit[n,h] = x[n,:].wx[h,:];
// per-segment softmax; out[h*N + n].
//
// Round 8: wave-per-segment, row-sequential x reads, RPL=2.
//  R4 post-mortem: RPL=4 q-outer gave each wave a 40KB x footprint swept 10x
//  (per q) -> L1 (32KB) + L2 thrash, FETCH 310MB (~4x of x), 104us.
//  RPL=2 keeps footprint 20KB <= L1 (each line fetched once) while still
//  halving wx ds_read_b128 count vs 1 row/lane. Keeps: 1-wave blocks (no
//  barriers, good balance), LDS logit cache (spill-proof, WRITE=8MB ideal).

#define NROWS 500000
#define DIM 40
#define NQ (DIM / 4)     // 10 float4 per row
#define NSEG 2048
#define DOTD 64
#define NH 4
#define PBLOCK 256
#define CROWS 512        // LDS cache rows (stat max segment len ~300)

// ---- prep: segment bounds (with gap fill for empty segments) + wx fold ----
__global__ __launch_bounds__(PBLOCK) void prep_kernel(
    const int* __restrict__ seg,    // [N], sorted
    const float* __restrict__ Wk,   // [168, 256]
    const float* __restrict__ Wq,   // [4, 64]
    int* __restrict__ seg_start,    // [NSEG]
    int* __restrict__ seg_end,      // [NSEG]
    float* __restrict__ wxg)        // [NH*DIM], layout h*DIM+d
{
    const int tid = (int)threadIdx.x;
    const int n = (int)(blockIdx.x * PBLOCK + tid);

    if (blockIdx.x == 0 && tid < DIM * NH) {
        const int h = tid / DIM;
        const int d = tid - h * DIM;
        const float* wkp = Wk + d * (NH * DOTD) + h * DOTD;
        const float* wqp = Wq + h * DOTD;
        float acc = 0.f;
        #pragma unroll
        for (int j = 0; j < DOTD; ++j) acc += wkp[j] * wqp[j];
        wxg[h * DIM + d] = acc * 0.125f;  // fold 1/sqrt(64)
    }

    if (n < NROWS) {
        const int s = seg[n];
        if (n == 0) {
            seg_start[s] = 0;
            for (int t = 0; t < s; ++t) { seg_start[t] = 0; seg_end[t] = 0; }
        } else {
            const int sp = seg[n - 1];
            if (sp != s) {
                seg_start[s] = n;
                seg_end[sp] = n;
                for (int t = sp + 1; t < s; ++t) { seg_start[t] = n; seg_end[t] = n; }
            }
        }
        if (n == NROWS - 1) {
            seg_end[s] = NROWS;
            for (int t = s + 1; t < NSEG; ++t) { seg_start[t] = NROWS; seg_end[t] = NROWS; }
        }
    }
}

// recompute logits for one row (fallback for rows beyond the LDS cache;
// statistically never taken: cache covers 512 rows, max segment ~300)
__device__ __forceinline__ void recompute_logits(
    const float4* __restrict__ x4, const float (*wxl)[DIM], int n, float* a)
{
    #pragma unroll
    for (int h = 0; h < NH; ++h) a[h] = 0.f;
    #pragma unroll
    for (int q = 0; q < NQ; ++q) {
        const float4 v = x4[(size_t)n * NQ + q];
        #pragma unroll
        for (int h = 0; h < NH; ++h) {
            const float4 w = ((const float4*)wxl[h])[q];
            a[h] += v.x * w.x + v.y * w.y + v.z * w.z + v.w * w.w;
        }
    }
}

// ---- main: one wave (=one 64-thread block) per segment ----
__global__ __launch_bounds__(64) void seg_attn_kernel(
    const float* __restrict__ x,          // [N, 40]
    const int* __restrict__ seg_start,
    const int* __restrict__ seg_end,
    const float* __restrict__ wxg,        // [NH*DIM]
    float* __restrict__ out)              // [4, N]
{
    __shared__ __align__(16) float wxl[NH][DIM];   // 640 B
    __shared__ float cache[NH][CROWS];             // 8 KB logit->e cache

    const int lane = (int)threadIdx.x;
    const int s = (int)blockIdx.x;
    const int start = seg_start[s];
    const int rows = seg_end[s] - start;
    if (rows <= 0) return;   // uniform for the whole (1-wave) block

    {   // stage wx (flat copy; wxg already [NH][DIM])
        float* wf = &wxl[0][0];
        for (int t = lane; t < NH * DIM; t += 64) wf[t] = wxg[t];
    }
    __syncthreads();   // 1-wave block: cheap; publishes cross-lane wx

    const float4* x4 = (const float4*)x;
    const int sup = (rows + 127) >> 7;   // super-iterations of 128 rows

    // ---- pass 1: logits -> LDS cache + lane-local max ----
    // 2 rows/lane share each wx b128 read; per-lane x reads stay
    // row-sequential (2 row streams/lane, 20KB wave footprint <= L1).
    float lmax[NH];
    #pragma unroll
    for (int h = 0; h < NH; ++h) lmax[h] = -3.0e38f;

    for (int si = 0; si < sup; ++si) {
        const int i0 = (si << 7) + lane;
        const int i1 = i0 + 64;
        const bool p0 = i0 < rows;
        const bool p1 = i1 < rows;
        const float4* r0 = x4 + (size_t)(start + i0) * NQ;
        const float4* r1 = x4 + (size_t)(start + i1) * NQ;
        float a0[NH] = {0.f, 0.f, 0.f, 0.f};
        float a1[NH] = {0.f, 0.f, 0.f, 0.f};

        #pragma unroll
        for (int q = 0; q < NQ; ++q) {
            float4 w[NH];
            #pragma unroll
            for (int h = 0; h < NH; ++h) w[h] = ((const float4*)wxl[h])[q];
            if (p0) {
                const float4 v = r0[q];
                #pragma unroll
                for (int h = 0; h < NH; ++h)
                    a0[h] += v.x * w[h].x + v.y * w[h].y
                           + v.z * w[h].z + v.w * w[h].w;
            }
            if (p1) {
                const float4 v = r1[q];
                #pragma unroll
                for (int h = 0; h < NH; ++h)
                    a1[h] += v.x * w[h].x + v.y * w[h].y
                           + v.z * w[h].z + v.w * w[h].w;
            }
        }
        if (p0) {
            #pragma unroll
            for (int h = 0; h < NH; ++h) {
                if (i0 < CROWS) cache[h][i0] = a0[h];
                lmax[h] = fmaxf(lmax[h], a0[h]);
            }
        }
        if (p1) {
            #pragma unroll
            for (int h = 0; h < NH; ++h) {
                if (i1 < CROWS) cache[h][i1] = a1[h];
                lmax[h] = fmaxf(lmax[h], a1[h]);
            }
        }
    }

    // ---- wave max reduce ----
    float m[NH];
    #pragma unroll
    for (int h = 0; h < NH; ++h) {
        float v = lmax[h];
        #pragma unroll
        for (int off = 32; off > 0; off >>= 1) v = fmaxf(v, __shfl_xor(v, off, 64));
        m[h] = v;
    }

    // ---- pass 2: e = exp(l-m) (store back to cache) + wave sum ----
    float lsum[NH] = {0.f, 0.f, 0.f, 0.f};
    for (int i = lane; i < rows; i += 64) {
        if (i < CROWS) {
            #pragma unroll
            for (int h = 0; h < NH; ++h) {
                const float e = __expf(cache[h][i] - m[h]);
                cache[h][i] = e;
                lsum[h] += e;
            }
        } else {  // stat-never fallback
            float a[NH];
            recompute_logits(x4, wxl, start + i, a);
            #pragma unroll
            for (int h = 0; h < NH; ++h) lsum[h] += __expf(a[h] - m[h]);
        }
    }
    float rden[NH];
    #pragma unroll
    for (int h = 0; h < NH; ++h) {
        float v = lsum[h];
        #pragma unroll
        for (int off = 32; off > 0; off >>= 1) v += __shfl_xor(v, off, 64);
        rden[h] = 1.0f / v;
    }

    // ---- pass 3: write normalized outputs (coalesced per h) ----
    for (int i = lane; i < rows; i += 64) {
        const int n = start + i;
        if (i < CROWS) {
            #pragma unroll
            for (int h = 0; h < NH; ++h)
                out[(size_t)h * NROWS + n] = cache[h][i] * rden[h];
        } else {  // stat-never fallback
            float a[NH];
            recompute_logits(x4, wxl, n, a);
            #pragma unroll
            for (int h = 0; h < NH; ++h)
                out[(size_t)h * NROWS + n] = __expf(a[h] - m[h]) * rden[h];
        }
    }
}

extern "C" void kernel_launch(void* const* d_in, const int* in_sizes, int n_in,
                              void* d_out, int out_size, void* d_ws, size_t ws_size,
                              hipStream_t stream) {
    const float* x  = (const float*)d_in[0];
    const int* seg  = (const int*)d_in[1];
    const float* Wk = (const float*)d_in[11];
    const float* Wq = (const float*)d_in[12];
    float* out = (float*)d_out;

    int* seg_start = (int*)d_ws;                  // [NSEG]
    int* seg_end   = seg_start + NSEG;            // [NSEG]
    float* wxg     = (float*)(seg_end + NSEG);    // [NH*DIM]

    hipLaunchKernelGGL(prep_kernel, dim3((NROWS + PBLOCK - 1) / PBLOCK), dim3(PBLOCK),
                       0, stream, seg, Wk, Wq, seg_start, seg_end, wxg);
    hipLaunchKernelGGL(seg_attn_kernel, dim3(NSEG), dim3(64),
                       0, stream, x, seg_start, seg_end, wxg, out);
}

// Round 6
// 157.803 us; speedup vs baseline: 1.3852x; 1.0906x over previous
//
#include <hip/hip_runtime.h>
#include <math.h>

// Output = segment_softmax over logits that depend ONLY on the inputs part of
// combined @ W_k: the agg(segment-mean MLP) contribution is constant within a
// segment and cancels exactly in the segment softmax (shift invariance).
// wx[h][d] = sum_j Wk[d, h*64+j]*Wq[h,j] / 8;  logit[n,h] = x[n,:].wx[h,:];
// per-segment softmax; out[h*N + n].
//
// Round 9: DECOUPLED two-phase design.
//  R5 post-mortem: the fused wave-per-segment kernel is latency-bound
//  (Occupancy 18.7%, VALUBusy 7%, 2.5 TB/s) because grid = 2048 one-wave
//  blocks = 8 waves/CU cap, too few to hide ~900cy HBM latency while
//  streaming 80MB of x. Split:
//   - logits_kernel: 1 thread/row, ~500k threads (~30 waves/CU), reads x
//     once, writes logit[4][N] (8MB) to ws. Pure streaming at full occupancy.
//   - seg_softmax_kernel: wave-per-segment on the 8MB logit planes (not the
//     80MB x) -> parallelism cap is harmless. LDS cache is per-lane only
//     (i = lane mod 64) -> no barriers at all. Spill-proof (R3-proven).
//  Cost: +16MB logit round-trip; gain: 4x wave parallelism on the 80MB phase.

#define NROWS 500000
#define DIM 40
#define NQ (DIM / 4)     // 10 float4 per row
#define NSEG 2048
#define DOTD 64
#define NH 4
#define PBLOCK 256
#define CROWS 512        // LDS cache rows (stat max segment len ~300)

// ---- prep: segment bounds (with gap fill for empty segments) + wx fold ----
__global__ __launch_bounds__(PBLOCK) void prep_kernel(
    const int* __restrict__ seg,    // [N], sorted
    const float* __restrict__ Wk,   // [168, 256]
    const float* __restrict__ Wq,   // [4, 64]
    int* __restrict__ seg_start,    // [NSEG]
    int* __restrict__ seg_end,      // [NSEG]
    float* __restrict__ wxg)        // [NH*DIM], layout h*DIM+d
{
    const int tid = (int)threadIdx.x;
    const int n = (int)(blockIdx.x * PBLOCK + tid);

    if (blockIdx.x == 0 && tid < DIM * NH) {
        const int h = tid / DIM;
        const int d = tid - h * DIM;
        const float* wkp = Wk + d * (NH * DOTD) + h * DOTD;
        const float* wqp = Wq + h * DOTD;
        float acc = 0.f;
        #pragma unroll
        for (int j = 0; j < DOTD; ++j) acc += wkp[j] * wqp[j];
        wxg[h * DIM + d] = acc * 0.125f;  // fold 1/sqrt(64)
    }

    if (n < NROWS) {
        const int s = seg[n];
        if (n == 0) {
            seg_start[s] = 0;
            for (int t = 0; t < s; ++t) { seg_start[t] = 0; seg_end[t] = 0; }
        } else {
            const int sp = seg[n - 1];
            if (sp != s) {
                seg_start[s] = n;
                seg_end[sp] = n;
                for (int t = sp + 1; t < s; ++t) { seg_start[t] = n; seg_end[t] = n; }
            }
        }
        if (n == NROWS - 1) {
            seg_end[s] = NROWS;
            for (int t = s + 1; t < NSEG; ++t) { seg_start[t] = NROWS; seg_end[t] = NROWS; }
        }
    }
}

// ---- phase 1: logits for all rows at full grid parallelism ----
__global__ __launch_bounds__(PBLOCK) void logits_kernel(
    const float* __restrict__ x,          // [N, 40]
    const float* __restrict__ wxg,        // [NH*DIM]
    float* __restrict__ logit)            // [NH][NROWS] planes in ws
{
    __shared__ __align__(16) float wxl[NH][DIM];   // 640 B

    const int tid = (int)threadIdx.x;
    {
        float* wf = &wxl[0][0];
        for (int t = tid; t < NH * DIM; t += PBLOCK) wf[t] = wxg[t];
    }
    __syncthreads();

    const int n = (int)(blockIdx.x * PBLOCK + tid);
    if (n >= NROWS) return;

    const float4* xr = (const float4*)(x + (size_t)n * DIM);
    float a[NH] = {0.f, 0.f, 0.f, 0.f};
    #pragma unroll
    for (int q = 0; q < NQ; ++q) {
        const float4 v = xr[q];
        #pragma unroll
        for (int h = 0; h < NH; ++h) {
            const float4 w = ((const float4*)wxl[h])[q];   // LDS broadcast
            a[h] += v.x * w.x + v.y * w.y + v.z * w.z + v.w * w.w;
        }
    }
    #pragma unroll
    for (int h = 0; h < NH; ++h)
        logit[(size_t)h * NROWS + n] = a[h];               // coalesced per h
}

// ---- phase 2: per-segment softmax over precomputed logits ----
// LDS cache is strictly per-lane (i = lane mod 64): no barriers needed.
__global__ __launch_bounds__(64) void seg_softmax_kernel(
    const float* __restrict__ logit,      // [NH][NROWS]
    const int* __restrict__ seg_start,
    const int* __restrict__ seg_end,
    float* __restrict__ out)              // [4, N]
{
    __shared__ float cache[NH][CROWS];    // 8 KB, per-lane slots only

    const int lane = (int)threadIdx.x;
    const int s = (int)blockIdx.x;
    const int start = seg_start[s];
    const int rows = seg_end[s] - start;
    if (rows <= 0) return;

    // ---- pass 1: load logits -> LDS + lane-local max ----
    float lmax[NH];
    #pragma unroll
    for (int h = 0; h < NH; ++h) lmax[h] = -3.0e38f;

    for (int i = lane; i < rows; i += 64) {
        #pragma unroll
        for (int h = 0; h < NH; ++h) {
            const float v = logit[(size_t)h * NROWS + start + i];
            if (i < CROWS) cache[h][i] = v;
            lmax[h] = fmaxf(lmax[h], v);
        }
    }

    // ---- wave max reduce ----
    float m[NH];
    #pragma unroll
    for (int h = 0; h < NH; ++h) {
        float v = lmax[h];
        #pragma unroll
        for (int off = 32; off > 0; off >>= 1) v = fmaxf(v, __shfl_xor(v, off, 64));
        m[h] = v;
    }

    // ---- pass 2: e = exp(l-m) (store back to LDS) + wave sum ----
    float lsum[NH] = {0.f, 0.f, 0.f, 0.f};
    for (int i = lane; i < rows; i += 64) {
        #pragma unroll
        for (int h = 0; h < NH; ++h) {
            const float l = (i < CROWS) ? cache[h][i]
                                        : logit[(size_t)h * NROWS + start + i];
            const float e = __expf(l - m[h]);
            if (i < CROWS) cache[h][i] = e;
            lsum[h] += e;
        }
    }
    float rden[NH];
    #pragma unroll
    for (int h = 0; h < NH; ++h) {
        float v = lsum[h];
        #pragma unroll
        for (int off = 32; off > 0; off >>= 1) v += __shfl_xor(v, off, 64);
        rden[h] = 1.0f / v;
    }

    // ---- pass 3: write normalized outputs (coalesced per h) ----
    for (int i = lane; i < rows; i += 64) {
        const int n = start + i;
        #pragma unroll
        for (int h = 0; h < NH; ++h) {
            const float e = (i < CROWS)
                ? cache[h][i]
                : __expf(logit[(size_t)h * NROWS + n] - m[h]);
            out[(size_t)h * NROWS + n] = e * rden[h];
        }
    }
}

extern "C" void kernel_launch(void* const* d_in, const int* in_sizes, int n_in,
                              void* d_out, int out_size, void* d_ws, size_t ws_size,
                              hipStream_t stream) {
    const float* x  = (const float*)d_in[0];
    const int* seg  = (const int*)d_in[1];
    const float* Wk = (const float*)d_in[11];
    const float* Wq = (const float*)d_in[12];
    float* out = (float*)d_out;

    int* seg_start = (int*)d_ws;                  // [NSEG]
    int* seg_end   = seg_start + NSEG;            // [NSEG]
    float* wxg     = (float*)(seg_end + NSEG);    // [NH*DIM] (256 slots)
    float* logit   = wxg + 256;                   // [NH*NROWS] = 8 MB

    const int nblk = (NROWS + PBLOCK - 1) / PBLOCK;
    hipLaunchKernelGGL(prep_kernel, dim3(nblk), dim3(PBLOCK),
                       0, stream, seg, Wk, Wq, seg_start, seg_end, wxg);
    hipLaunchKernelGGL(logits_kernel, dim3(nblk), dim3(PBLOCK),
                       0, stream, x, wxg, logit);
    hipLaunchKernelGGL(seg_softmax_kernel, dim3(NSEG), dim3(64),
                       0, stream, logit, seg_start, seg_end, out);
}